// Round 9
// baseline (128.382 us; speedup 1.0000x reference)
//
#include <hip/hip_runtime.h>
#include <math.h>

typedef __attribute__((ext_vector_type(8))) short bf16x8;
typedef __attribute__((ext_vector_type(4))) float f32x4;

#define AAM_COS_M 0.9800665778412416f
#define AAM_SIN_M 0.19866933079506122f
#define AAM_TH   (-0.9800665778412416f)
#define AAM_MM    0.03973386615901225f
#define C_CLS 5994

__device__ inline ushort f2bf(float f) {
    unsigned x = __float_as_uint(f);
    return (ushort)((x + 0x7fffu + ((x >> 16) & 1u)) >> 16);
}

// async global->LDS, 16B per lane. LDS dest is wave-uniform base + lane*16.
__device__ __forceinline__ void gload16(const void* g, void* lds) {
    __builtin_amdgcn_global_load_lds(
        (const __attribute__((address_space(1))) unsigned int*)g,
        (__attribute__((address_space(3))) unsigned int*)lds, 16, 0, 0);
}

// ---------------- prep: Wfc->bf16 (256 blk) + rownorm_w+pad (1536 blk) ------
__global__ __launch_bounds__(256) void prep(const float* __restrict__ Wfc,
                                            const float* __restrict__ Waam,
                                            ushort* __restrict__ wfcb,
                                            ushort* __restrict__ Wn) {
    const int b = blockIdx.x;
    if (b < 256) {
        int i = b * 256 + threadIdx.x;
        float4 v = ((const float4*)Wfc)[i];
        ushort4 o;
        o.x = f2bf(v.x); o.y = f2bf(v.y); o.z = f2bf(v.z); o.w = f2bf(v.w);
        ((ushort4*)wfcb)[i] = o;
    } else {
        const int wave = threadIdx.x >> 6, lane = threadIdx.x & 63;
        const int row = (b - 256) * 4 + wave;
        ushort4 o;
        if (row < C_CLS) {
            float4 v = ((const float4*)&Waam[(size_t)row * 256])[lane];
            float ss = v.x * v.x + v.y * v.y + v.z * v.z + v.w * v.w;
#pragma unroll
            for (int m = 32; m >= 1; m >>= 1) ss += __shfl_xor(ss, m, 64);
            float sc = 1.f / fmaxf(sqrtf(ss), 1e-12f);
            o.x = f2bf(v.x * sc); o.y = f2bf(v.y * sc);
            o.z = f2bf(v.z * sc); o.w = f2bf(v.w * sc);
        } else {
            o.x = 0; o.y = 0; o.z = 0; o.w = 0;
        }
        ((ushort4*)&Wn[(size_t)row * 256])[lane] = o;
    }
}

// ---------------- fused fc GEMM + bias + row-L2-norm -> En bf16 -------------
// Tile: 16 rows x 256 cols (full N), K=1024, BK=32, double-buffered.
// Grid 256 blocks, 4 waves; wave w owns cols w*64..w*64+64 (4 j-frags), all 16 rows.
// A staged as f32 (x read directly), converted to bf16 in-register.
// Both tiles XOR-swizzled on both sides (gload16 writes linearly; rule #21).
__global__ __launch_bounds__(256) void fc_norm(const float* __restrict__ X,
                                               const ushort* __restrict__ Bm,
                                               const float* __restrict__ bias,
                                               ushort* __restrict__ En) {
    __shared__ float  Af[2][16 * 32];     // 2 KB per buf
    __shared__ ushort Bs[2][256 * 32];    // 16 KB per buf
    __shared__ float  red[4][16];
    const int tid = threadIdx.x, lane = tid & 63, w = tid >> 6;
    const int lx = lane & 15, lg = lane >> 4;
    const int rb = blockIdx.x * 16;

    // A staging (waves 0,1): 8 rows x 32 f32 each; slot XOR row&7
    const int arow = lane >> 3;                       // 0..7 within half
    const int agcol = ((lane & 7) ^ arow) * 4;        // f32 col
    // B staging (all waves, 4 segs): 16 rows x 32 bf16; slot XOR row&3
    const int brow = lane >> 2;                       // 0..15 within seg
    const int bgcol = (((lane & 3) ^ (brow & 3)) * 8);// bf16 col

    f32x4 zero = {0.f, 0.f, 0.f, 0.f};
    f32x4 acc[4];
#pragma unroll
    for (int j = 0; j < 4; ++j) acc[j] = zero;

#define FC_STAGE(buf, k0) do {                                                  \
    if (w < 2)                                                                  \
        gload16(&X[(size_t)(rb + w * 8 + arow) * 1024 + (k0) + agcol],          \
                &Af[buf][w * 256]);                                             \
    _Pragma("unroll")                                                           \
    for (int s_ = 0; s_ < 4; ++s_) {                                            \
        int r0_ = w * 64 + s_ * 16;                                             \
        gload16(&Bm[(size_t)(r0_ + brow) * 1024 + (k0) + bgcol],                \
                &Bs[buf][r0_ * 32]);                                            \
    } } while (0)

    int cur = 0;
    FC_STAGE(0, 0);
    __syncthreads();

    for (int g = 0; g < 32; ++g) {
        if (g < 31) FC_STAGE(cur ^ 1, (g + 1) * 32);
        // A frag: row lx, k = lg*8..+8 (two swizzled float4 reads), cvt->bf16
        float4 fa0 = *(const float4*)&Af[cur][lx * 32 + (((lg * 2)     ^ (lx & 7)) * 4)];
        float4 fa1 = *(const float4*)&Af[cur][lx * 32 + (((lg * 2 + 1) ^ (lx & 7)) * 4)];
        bf16x8 af;
        af[0] = (short)f2bf(fa0.x); af[1] = (short)f2bf(fa0.y);
        af[2] = (short)f2bf(fa0.z); af[3] = (short)f2bf(fa0.w);
        af[4] = (short)f2bf(fa1.x); af[5] = (short)f2bf(fa1.y);
        af[6] = (short)f2bf(fa1.z); af[7] = (short)f2bf(fa1.w);
        bf16x8 bv[4];
#pragma unroll
        for (int j = 0; j < 4; ++j) {
            int rq = w * 64 + j * 16 + lx;
            bv[j] = *(const bf16x8*)&Bs[cur][rq * 32 + ((lg ^ (rq & 3)) * 8)];
        }
#pragma unroll
        for (int j = 0; j < 4; ++j)
            acc[j] = __builtin_amdgcn_mfma_f32_16x16x32_bf16(af, bv[j], acc[j], 0, 0, 0);
        __syncthreads();
        cur ^= 1;
    }
#undef FC_STAGE

    // epilogue: bias, row sq-sum (16 lanes + cross-wave), normalize, write bf16
    float v[4][4];
#pragma unroll
    for (int j = 0; j < 4; ++j) {
        float bb = bias[w * 64 + j * 16 + lx];
#pragma unroll
        for (int q = 0; q < 4; ++q) v[j][q] = acc[j][q] + bb;
    }
    float sq[4];
#pragma unroll
    for (int q = 0; q < 4; ++q) {
        float s = v[0][q] * v[0][q] + v[1][q] * v[1][q]
                + v[2][q] * v[2][q] + v[3][q] * v[3][q];
#pragma unroll
        for (int m = 8; m >= 1; m >>= 1) s += __shfl_xor(s, m, 64);
        sq[q] = s;    // row (lg*4+q) partial over this wave's 64 cols
    }
    if (lx == 0) {
#pragma unroll
        for (int q = 0; q < 4; ++q) red[w][lg * 4 + q] = sq[q];
    }
    __syncthreads();
#pragma unroll
    for (int q = 0; q < 4; ++q) {
        int row = lg * 4 + q;
        float tot = red[0][row] + red[1][row] + red[2][row] + red[3][row];
        float sc = 1.f / fmaxf(sqrtf(tot), 1e-12f);
#pragma unroll
        for (int j = 0; j < 4; ++j)
            En[(size_t)(rb + row) * 256 + w * 64 + j * 16 + lx] = f2bf(v[j][q] * sc);
    }
}

// ---------------- cosine GEMM + exp-sum partials + label-cos capture --------
// (unchanged from R8: proven) --------------------------------------------
__global__ __launch_bounds__(256, 2) void aam_mfma(const ushort* __restrict__ A,
                                                   const ushort* __restrict__ Bm,
                                                   const int* __restrict__ lab,
                                                   float* __restrict__ ps,
                                                   float* __restrict__ cosl) {
    __shared__ ushort As[2][128 * 64];
    __shared__ ushort Bs[2][128 * 64];
    const int tid = threadIdx.x, lane = tid & 63, w = tid >> 6;
    const int wr = w >> 1, wc = w & 1;
    const int lx = lane & 15, lg = lane >> 4;
    const int rb = blockIdx.x * 128;
    const int split = blockIdx.y;

    const int lrow = lane >> 3;
    const int gcol = ((lane & 7) ^ lrow) * 8;

    int labs[16];
#pragma unroll
    for (int idx = 0; idx < 16; ++idx)
        labs[idx] = lab[rb + wr * 64 + (idx >> 2) * 16 + lg * 4 + (idx & 3)];

    float srun[16];
#pragma unroll
    for (int idx = 0; idx < 16; ++idx) srun[idx] = 0.f;

    f32x4 zero = {0.f, 0.f, 0.f, 0.f};
    f32x4 acc[4][4];
#pragma unroll
    for (int i = 0; i < 4; ++i)
#pragma unroll
        for (int j = 0; j < 4; ++j) acc[i][j] = zero;

#define AAM_STAGE(buf, g) do {                                                  \
    int t_ = (g) >> 2, k0_ = ((g) & 3) * 64;                                    \
    int cb_ = split * 384 + t_ * 128;                                           \
    _Pragma("unroll")                                                           \
    for (int s_ = 0; s_ < 4; ++s_) {                                            \
        int r0_ = w * 32 + s_ * 8;                                              \
        gload16(&A[(size_t)(rb + r0_ + lrow) * 256 + k0_ + gcol],               \
                &As[buf][r0_ * 64]);                                            \
        gload16(&Bm[(size_t)(cb_ + r0_ + lrow) * 256 + k0_ + gcol],             \
                &Bs[buf][r0_ * 64]);                                            \
    } } while (0)

    int cur = 0;
    AAM_STAGE(0, 0);
    __syncthreads();

    for (int g = 0; g < 12; ++g) {
        if (g < 11) AAM_STAGE(cur ^ 1, g + 1);
#pragma unroll
        for (int kk = 0; kk < 2; ++kk) {
            bf16x8 af[4], bv[4];
#pragma unroll
            for (int f = 0; f < 4; ++f) {
                int ra = wr * 64 + f * 16 + lx;
                int ca = (lg + kk * 4) ^ (lx & 7);
                af[f] = *(const bf16x8*)&As[cur][ra * 64 + ca * 8];
                int rq = wc * 64 + f * 16 + lx;
                bv[f] = *(const bf16x8*)&Bs[cur][rq * 64 + ca * 8];
            }
#pragma unroll
            for (int i = 0; i < 4; ++i)
#pragma unroll
                for (int j = 0; j < 4; ++j)
                    acc[i][j] = __builtin_amdgcn_mfma_f32_16x16x32_bf16(af[i], bv[j], acc[i][j], 0, 0, 0);
        }
        if ((g & 3) == 3) {
            int cb_ = split * 384 + (g >> 2) * 128;
#pragma unroll
            for (int j = 0; j < 4; ++j) {
                int c = cb_ + wc * 64 + j * 16 + lx;
                if (c < C_CLS) {
#pragma unroll
                    for (int i = 0; i < 4; ++i)
#pragma unroll
                        for (int r = 0; r < 4; ++r) {
                            int idx = i * 4 + r;
                            float cosv = acc[i][j][r];
                            srun[idx] += __expf(30.f * cosv - 30.f);
                            if (c == labs[idx])
                                cosl[rb + wr * 64 + i * 16 + lg * 4 + r] = cosv;
                        }
                }
            }
#pragma unroll
            for (int i = 0; i < 4; ++i)
#pragma unroll
                for (int j = 0; j < 4; ++j) acc[i][j] = zero;
        }
        __syncthreads();
        cur ^= 1;
    }
#undef AAM_STAGE

#pragma unroll
    for (int idx = 0; idx < 16; ++idx) {
#pragma unroll
        for (int msk = 1; msk < 16; msk <<= 1)
            srun[idx] += __shfl_xor(srun[idx], msk, 64);
        if (lx == 0) {
            int row = rb + wr * 64 + (idx >> 2) * 16 + lg * 4 + (idx & 3);
            ps[(size_t)row * 32 + split * 2 + wc] = srun[idx];
        }
    }
}

// ---------------- stage 1: thread-per-row nll, 16 block partials ------------
__global__ __launch_bounds__(256) void reduce_nll(const float* __restrict__ ps,
                                                  const float* __restrict__ cosl,
                                                  float* __restrict__ partial) {
    __shared__ float red[4];
    const int row = blockIdx.x * 256 + threadIdx.x;
    const int wave = threadIdx.x >> 6, lane = threadIdx.x & 63;
    float s = 0.f;
#pragma unroll
    for (int q = 0; q < 8; ++q) {
        float4 v = ((const float4*)&ps[(size_t)row * 32])[q];
        s += v.x + v.y + v.z + v.w;
    }
    float cv = cosl[row];
    float sine = sqrtf(fmaxf(1.f - cv * cv, 0.f));
    float phi = cv * AAM_COS_M - sine * AAM_SIN_M;
    phi = ((cv - AAM_TH) > 0.f) ? phi : (cv - AAM_MM);
    float denom = s - __expf(30.f * cv - 30.f) + __expf(30.f * phi - 30.f);
    float nll = 30.f + logf(denom) - 30.f * phi;
#pragma unroll
    for (int m = 32; m >= 1; m >>= 1) nll += __shfl_xor(nll, m, 64);
    if (lane == 0) red[wave] = nll;
    __syncthreads();
    if (threadIdx.x == 0)
        partial[blockIdx.x] = red[0] + red[1] + red[2] + red[3];
}

// ---------------- stage 2: sum 16 partials -> mean --------------------------
__global__ __launch_bounds__(64) void final_reduce(const float* __restrict__ partial,
                                                   float* __restrict__ out) {
    const int lane = threadIdx.x;
    float v = (lane < 16) ? partial[lane] : 0.f;
#pragma unroll
    for (int m = 32; m >= 1; m >>= 1) v += __shfl_xor(v, m, 64);
    if (lane == 0) out[0] = v * (1.f / 4096.f);
}

extern "C" void kernel_launch(void* const* d_in, const int* in_sizes, int n_in,
                              void* d_out, int out_size, void* d_ws, size_t ws_size,
                              hipStream_t stream) {
    const float* x    = (const float*)d_in[0];
    const int*   lab  = (const int*)d_in[1];
    const float* Wfc  = (const float*)d_in[2];
    const float* bfc  = (const float*)d_in[3];
    const float* Waam = (const float*)d_in[4];
    float* out = (float*)d_out;

    char* ws = (char*)d_ws;
    ushort* En   = (ushort*)(ws);                 // [0, 2097152)
    ushort* Wfcb = (ushort*)(ws + 2097152);       // [2097152, 2621440)
    ushort* Wn   = (ushort*)(ws + 2621440);       // [2621440, 5767168)
    float*  ps   = (float*) (ws + 5767168);       // 512 KB, layout [row*32+part]
    float*  cosl = (float*) (ws + 6291456);       // 16 KB
    float*  part = (float*) (ws + 6307840);       // 64 B

    prep<<<1792, 256, 0, stream>>>(Wfc, Waam, Wfcb, Wn);
    fc_norm<<<256, 256, 0, stream>>>(x, Wfcb, bfc, En);
    aam_mfma<<<dim3(32, 16), 256, 0, stream>>>(En, Wn, lab, ps, cosl);
    reduce_nll<<<16, 256, 0, stream>>>(ps, cosl, part);
    final_reduce<<<1, 64, 0, stream>>>(part, out);
}

// Round 10
// 121.966 us; speedup vs baseline: 1.0526x; 1.0526x over previous
//
#include <hip/hip_runtime.h>
#include <math.h>

typedef __attribute__((ext_vector_type(8))) short bf16x8;
typedef __attribute__((ext_vector_type(4))) float f32x4;

#define AAM_COS_M 0.9800665778412416f
#define AAM_SIN_M 0.19866933079506122f
#define AAM_TH   (-0.9800665778412416f)
#define AAM_MM    0.03973386615901225f
#define C_CLS 5994

__device__ inline ushort f2bf(float f) {
    unsigned x = __float_as_uint(f);
    return (ushort)((x + 0x7fffu + ((x >> 16) & 1u)) >> 16);
}

// async global->LDS, 16B per lane. LDS dest is wave-uniform base + lane*16.
__device__ __forceinline__ void gload16(const void* g, void* lds) {
    __builtin_amdgcn_global_load_lds(
        (const __attribute__((address_space(1))) unsigned int*)g,
        (__attribute__((address_space(3))) unsigned int*)lds, 16, 0, 0);
}

// ---------------- prep: Wfc -> bf16 (256 blocks) ----------------------------
__global__ __launch_bounds__(256) void prep(const float* __restrict__ Wfc,
                                            ushort* __restrict__ wfcb) {
    int i = blockIdx.x * 256 + threadIdx.x;
    float4 v = ((const float4*)Wfc)[i];
    ushort4 o;
    o.x = f2bf(v.x); o.y = f2bf(v.y); o.z = f2bf(v.z); o.w = f2bf(v.w);
    ((ushort4*)wfcb)[i] = o;
}

// ---------------- fcw: fused fc GEMM + bias + row-L2-norm -> En bf16,
//                  plus Waam row-norm role (blocks 128..255) -----------------
// fc role: 32 rows x 256 cols per block, K=1024, BK=64, double-buffered.
// 4 waves; wave w owns cols [w*64, w*64+64): 2 row-frags x 4 col-frags.
// A staged as f32 (x read directly), trunc-cast to bf16 in-register
// (row-normalize is scale-invariant -> trunc bias cancels).
// A swizzle: 16B-slot ^ (row&15); B swizzle: slot ^ (row&7). Both sides.
__global__ __launch_bounds__(256) void fcw(const float* __restrict__ X,
                                           const ushort* __restrict__ Bm,
                                           const float* __restrict__ bias,
                                           const float* __restrict__ Waam,
                                           ushort* __restrict__ En,
                                           ushort* __restrict__ Wn) {
    __shared__ float  Af[2][32 * 64];     // 8 KB per buf
    __shared__ ushort Bs[2][256 * 64];    // 32 KB per buf
    __shared__ float  red[4][32];
    const int tid = threadIdx.x, lane = tid & 63, w = tid >> 6;

    if (blockIdx.x >= 128) {              // -------- Waam row-normalize role
        const int base = (blockIdx.x - 128) * 48 + w * 12;
        for (int r = 0; r < 12; ++r) {
            const int row = base + r;
            ushort4 o;
            if (row < C_CLS) {
                float4 v = ((const float4*)&Waam[(size_t)row * 256])[lane];
                float ss = v.x * v.x + v.y * v.y + v.z * v.z + v.w * v.w;
#pragma unroll
                for (int m = 32; m >= 1; m >>= 1) ss += __shfl_xor(ss, m, 64);
                float sc = 1.f / fmaxf(sqrtf(ss), 1e-12f);
                o.x = f2bf(v.x * sc); o.y = f2bf(v.y * sc);
                o.z = f2bf(v.z * sc); o.w = f2bf(v.w * sc);
            } else {
                o.x = 0; o.y = 0; o.z = 0; o.w = 0;
            }
            ((ushort4*)&Wn[(size_t)row * 256])[lane] = o;
        }
        return;
    }

    // ---------------- fc role ----------------
    const int lx = lane & 15, lg = lane >> 4;
    const int rb = blockIdx.x * 32;

    f32x4 zero = {0.f, 0.f, 0.f, 0.f};
    f32x4 acc[2][4];
#pragma unroll
    for (int i = 0; i < 2; ++i)
#pragma unroll
        for (int j = 0; j < 4; ++j) acc[i][j] = zero;

#define FCW_STAGE(buf, k0) do {                                                \
    _Pragma("unroll")                                                          \
    for (int g_ = 0; g_ < 2; ++g_) {                                           \
        int r_ = w * 8 + g_ * 4 + (lane >> 4);                                 \
        int gc_ = ((lane & 15) ^ (r_ & 15)) * 4;                               \
        gload16(&X[(size_t)(rb + r_) * 1024 + (k0) + gc_],                     \
                &Af[buf][(w * 8 + g_ * 4) * 64]);                              \
    }                                                                          \
    _Pragma("unroll")                                                          \
    for (int s_ = 0; s_ < 8; ++s_) {                                           \
        int r_ = w * 64 + s_ * 8 + (lane >> 3);                                \
        int gc_ = ((lane & 7) ^ (r_ & 7)) * 8;                                 \
        gload16(&Bm[(size_t)r_ * 1024 + (k0) + gc_],                           \
                &Bs[buf][(w * 64 + s_ * 8) * 64]);                             \
    } } while (0)

    int cur = 0;
    FCW_STAGE(0, 0);
    __syncthreads();

    for (int g = 0; g < 16; ++g) {
        if (g < 15) FCW_STAGE(cur ^ 1, (g + 1) * 64);
#pragma unroll
        for (int kk = 0; kk < 2; ++kk) {
            bf16x8 af[2];
#pragma unroll
            for (int i = 0; i < 2; ++i) {
                int ra = i * 16 + lx;
                int s0 = kk * 8 + lg * 2;
                float4 fa0 = *(const float4*)&Af[cur][ra * 64 + (((s0    ) ^ (ra & 15)) * 4)];
                float4 fa1 = *(const float4*)&Af[cur][ra * 64 + (((s0 + 1) ^ (ra & 15)) * 4)];
                af[i][0] = (short)(__float_as_uint(fa0.x) >> 16);
                af[i][1] = (short)(__float_as_uint(fa0.y) >> 16);
                af[i][2] = (short)(__float_as_uint(fa0.z) >> 16);
                af[i][3] = (short)(__float_as_uint(fa0.w) >> 16);
                af[i][4] = (short)(__float_as_uint(fa1.x) >> 16);
                af[i][5] = (short)(__float_as_uint(fa1.y) >> 16);
                af[i][6] = (short)(__float_as_uint(fa1.z) >> 16);
                af[i][7] = (short)(__float_as_uint(fa1.w) >> 16);
            }
            bf16x8 bv[4];
#pragma unroll
            for (int j = 0; j < 4; ++j) {
                int rq = w * 64 + j * 16 + lx;
                bv[j] = *(const bf16x8*)&Bs[cur][rq * 64 + (((kk * 4 + lg) ^ (rq & 7)) * 8)];
            }
#pragma unroll
            for (int i = 0; i < 2; ++i)
#pragma unroll
                for (int j = 0; j < 4; ++j)
                    acc[i][j] = __builtin_amdgcn_mfma_f32_16x16x32_bf16(af[i], bv[j], acc[i][j], 0, 0, 0);
        }
        __syncthreads();
        cur ^= 1;
    }
#undef FCW_STAGE

    // epilogue: bias, row sq-sum (16-lane shfl + cross-wave LDS), norm, write
    float v[2][4][4];
#pragma unroll
    for (int j = 0; j < 4; ++j) {
        float bb = bias[w * 64 + j * 16 + lx];
#pragma unroll
        for (int i = 0; i < 2; ++i)
#pragma unroll
            for (int q = 0; q < 4; ++q) v[i][j][q] = acc[i][j][q] + bb;
    }
#pragma unroll
    for (int i = 0; i < 2; ++i)
#pragma unroll
        for (int q = 0; q < 4; ++q) {
            float s = v[i][0][q] * v[i][0][q] + v[i][1][q] * v[i][1][q]
                    + v[i][2][q] * v[i][2][q] + v[i][3][q] * v[i][3][q];
#pragma unroll
            for (int m = 8; m >= 1; m >>= 1) s += __shfl_xor(s, m, 64);
            if (lx == 0) red[w][i * 16 + lg * 4 + q] = s;
        }
    __syncthreads();
#pragma unroll
    for (int i = 0; i < 2; ++i)
#pragma unroll
        for (int q = 0; q < 4; ++q) {
            int row = i * 16 + lg * 4 + q;
            float tot = red[0][row] + red[1][row] + red[2][row] + red[3][row];
            float sc = 1.f / fmaxf(sqrtf(tot), 1e-12f);
#pragma unroll
            for (int j = 0; j < 4; ++j)
                En[(size_t)(rb + row) * 256 + w * 64 + j * 16 + lx] = f2bf(v[i][j][q] * sc);
        }
}

// ---------------- cosine GEMM + exp-sum partials + label-cos capture --------
// (unchanged, proven) ---------------------------------------------------------
__global__ __launch_bounds__(256, 2) void aam_mfma(const ushort* __restrict__ A,
                                                   const ushort* __restrict__ Bm,
                                                   const int* __restrict__ lab,
                                                   float* __restrict__ ps,
                                                   float* __restrict__ cosl) {
    __shared__ ushort As[2][128 * 64];
    __shared__ ushort Bs[2][128 * 64];
    const int tid = threadIdx.x, lane = tid & 63, w = tid >> 6;
    const int wr = w >> 1, wc = w & 1;
    const int lx = lane & 15, lg = lane >> 4;
    const int rb = blockIdx.x * 128;
    const int split = blockIdx.y;

    const int lrow = lane >> 3;
    const int gcol = ((lane & 7) ^ lrow) * 8;

    int labs[16];
#pragma unroll
    for (int idx = 0; idx < 16; ++idx)
        labs[idx] = lab[rb + wr * 64 + (idx >> 2) * 16 + lg * 4 + (idx & 3)];

    float srun[16];
#pragma unroll
    for (int idx = 0; idx < 16; ++idx) srun[idx] = 0.f;

    f32x4 zero = {0.f, 0.f, 0.f, 0.f};
    f32x4 acc[4][4];
#pragma unroll
    for (int i = 0; i < 4; ++i)
#pragma unroll
        for (int j = 0; j < 4; ++j) acc[i][j] = zero;

#define AAM_STAGE(buf, g) do {                                                  \
    int t_ = (g) >> 2, k0_ = ((g) & 3) * 64;                                    \
    int cb_ = split * 384 + t_ * 128;                                           \
    _Pragma("unroll")                                                           \
    for (int s_ = 0; s_ < 4; ++s_) {                                            \
        int r0_ = w * 32 + s_ * 8;                                              \
        gload16(&A[(size_t)(rb + r0_ + lrow) * 256 + k0_ + gcol],               \
                &As[buf][r0_ * 64]);                                            \
        gload16(&Bm[(size_t)(cb_ + r0_ + lrow) * 256 + k0_ + gcol],             \
                &Bs[buf][r0_ * 64]);                                            \
    } } while (0)

    int cur = 0;
    AAM_STAGE(0, 0);
    __syncthreads();

    for (int g = 0; g < 12; ++g) {
        if (g < 11) AAM_STAGE(cur ^ 1, g + 1);
#pragma unroll
        for (int kk = 0; kk < 2; ++kk) {
            bf16x8 af[4], bv[4];
#pragma unroll
            for (int f = 0; f < 4; ++f) {
                int ra = wr * 64 + f * 16 + lx;
                int ca = (lg + kk * 4) ^ (lx & 7);
                af[f] = *(const bf16x8*)&As[cur][ra * 64 + ca * 8];
                int rq = wc * 64 + f * 16 + lx;
                bv[f] = *(const bf16x8*)&Bs[cur][rq * 64 + ca * 8];
            }
#pragma unroll
            for (int i = 0; i < 4; ++i)
#pragma unroll
                for (int j = 0; j < 4; ++j)
                    acc[i][j] = __builtin_amdgcn_mfma_f32_16x16x32_bf16(af[i], bv[j], acc[i][j], 0, 0, 0);
        }
        if ((g & 3) == 3) {
            int cb_ = split * 384 + (g >> 2) * 128;
#pragma unroll
            for (int j = 0; j < 4; ++j) {
                int c = cb_ + wc * 64 + j * 16 + lx;
                if (c < C_CLS) {
#pragma unroll
                    for (int i = 0; i < 4; ++i)
#pragma unroll
                        for (int r = 0; r < 4; ++r) {
                            int idx = i * 4 + r;
                            float cosv = acc[i][j][r];
                            srun[idx] += __expf(30.f * cosv - 30.f);
                            if (c == labs[idx])
                                cosl[rb + wr * 64 + i * 16 + lg * 4 + r] = cosv;
                        }
                }
            }
#pragma unroll
            for (int i = 0; i < 4; ++i)
#pragma unroll
                for (int j = 0; j < 4; ++j) acc[i][j] = zero;
        }
        __syncthreads();
        cur ^= 1;
    }
#undef AAM_STAGE

#pragma unroll
    for (int idx = 0; idx < 16; ++idx) {
#pragma unroll
        for (int msk = 1; msk < 16; msk <<= 1)
            srun[idx] += __shfl_xor(srun[idx], msk, 64);
        if (lx == 0) {
            int row = rb + wr * 64 + (idx >> 2) * 16 + lg * 4 + (idx & 3);
            ps[(size_t)row * 32 + split * 2 + wc] = srun[idx];
        }
    }
}

// ---------------- stage 1: thread-per-row nll, 16 block partials ------------
__global__ __launch_bounds__(256) void reduce_nll(const float* __restrict__ ps,
                                                  const float* __restrict__ cosl,
                                                  float* __restrict__ partial) {
    __shared__ float red[4];
    const int row = blockIdx.x * 256 + threadIdx.x;
    const int wave = threadIdx.x >> 6, lane = threadIdx.x & 63;
    float s = 0.f;
#pragma unroll
    for (int q = 0; q < 8; ++q) {
        float4 v = ((const float4*)&ps[(size_t)row * 32])[q];
        s += v.x + v.y + v.z + v.w;
    }
    float cv = cosl[row];
    float sine = sqrtf(fmaxf(1.f - cv * cv, 0.f));
    float phi = cv * AAM_COS_M - sine * AAM_SIN_M;
    phi = ((cv - AAM_TH) > 0.f) ? phi : (cv - AAM_MM);
    float denom = s - __expf(30.f * cv - 30.f) + __expf(30.f * phi - 30.f);
    float nll = 30.f + logf(denom) - 30.f * phi;
#pragma unroll
    for (int m = 32; m >= 1; m >>= 1) nll += __shfl_xor(nll, m, 64);
    if (lane == 0) red[wave] = nll;
    __syncthreads();
    if (threadIdx.x == 0)
        partial[blockIdx.x] = red[0] + red[1] + red[2] + red[3];
}

// ---------------- stage 2: sum 16 partials -> mean --------------------------
__global__ __launch_bounds__(64) void final_reduce(const float* __restrict__ partial,
                                                   float* __restrict__ out) {
    const int lane = threadIdx.x;
    float v = (lane < 16) ? partial[lane] : 0.f;
#pragma unroll
    for (int m = 32; m >= 1; m >>= 1) v += __shfl_xor(v, m, 64);
    if (lane == 0) out[0] = v * (1.f / 4096.f);
}

extern "C" void kernel_launch(void* const* d_in, const int* in_sizes, int n_in,
                              void* d_out, int out_size, void* d_ws, size_t ws_size,
                              hipStream_t stream) {
    const float* x    = (const float*)d_in[0];
    const int*   lab  = (const int*)d_in[1];
    const float* Wfc  = (const float*)d_in[2];
    const float* bfc  = (const float*)d_in[3];
    const float* Waam = (const float*)d_in[4];
    float* out = (float*)d_out;

    char* ws = (char*)d_ws;
    ushort* Wfcb = (ushort*)(ws);                 // [0, 524288)
    ushort* En   = (ushort*)(ws + 524288);        // [524288, 2621440)
    ushort* Wn   = (ushort*)(ws + 2621440);       // [2621440, 5767168)
    float*  ps   = (float*) (ws + 5767168);       // 512 KB, layout [row*32+part]
    float*  cosl = (float*) (ws + 6291456);       // 16 KB
    float*  part = (float*) (ws + 6307840);       // 64 B

    prep<<<256, 256, 0, stream>>>(Wfc, Wfcb);
    fcw<<<256, 256, 0, stream>>>(x, Wfcb, bfc, Waam, En, Wn);
    aam_mfma<<<dim3(32, 16), 256, 0, stream>>>(En, Wn, lab, ps, cosl);
    reduce_nll<<<16, 256, 0, stream>>>(ps, cosl, part);
    final_reduce<<<1, 64, 0, stream>>>(part, out);
}